// Round 8
// baseline (135.427 us; speedup 1.0000x reference)
//
#include <hip/hip_runtime.h>
#include <hip/hip_bf16.h>
#include <stdint.h>

// Problem dims
constexpr int NB = 4;          // batch
constexpr int NF = 16;         // frames
constexpr int NH = 224, NW = 224;
constexpr int HWPIX = NH * NW;             // 50176
constexpr int NPIX = NB * NF * HWPIX;      // 3,211,264
constexpr int OC2 = 128;

typedef __attribute__((ext_vector_type(8))) __bf16 bf16x8;
typedef __attribute__((ext_vector_type(4))) float f32x4;

#define MFMA16(a, b, c) __builtin_amdgcn_mfma_f32_16x16x32_bf16(a, b, c, 0, 0, 0)

__device__ __forceinline__ ushort bf16u(float f) {
  __hip_bfloat16 h = __float2bfloat16(f);
  return *(ushort*)&h;
}

// ---------------- fused gray + uniform LBP codes (u8) + per-tile max ----------
__global__ __launch_bounds__(256) void graylbp_kernel(const float* __restrict__ x,
                                                      unsigned char* __restrict__ lbpc,
                                                      int* __restrict__ blockmax) {
  __shared__ float sg[18 * 18];
  const int tile = blockIdx.x;                          // 0..195
  const int frame = blockIdx.y;                         // 0..63
  const int ty = tile / 14, tx = tile - ty * 14;
  const int b = frame >> 4, f = frame & 15;
  const float* xb = x + ((size_t)b * 3 * NF + f) * HWPIX;   // channel stride NF*HWPIX

  for (int e = threadIdx.x; e < 324; e += 256) {
    int r = e / 18, cc = e - 18 * r;
    int y = ty * 16 + r - 1, xx = tx * 16 + cc - 1;
    float v = 0.0f;
    if ((unsigned)y < (unsigned)NH && (unsigned)xx < (unsigned)NW) {
      size_t o = (size_t)y * NW + xx;
      float s = xb[o] + xb[o + (size_t)NF * HWPIX] + xb[o + 2 * (size_t)NF * HWPIX];
      v = floorf((s / 3.0f) * 255.0f);
    }
    sg[e] = v;
  }
  __syncthreads();

  const int r = threadIdx.x >> 4, cc = threadIdx.x & 15;
  float n[3][3];
#pragma unroll
  for (int dy = 0; dy < 3; ++dy)
#pragma unroll
    for (int dx = 0; dx < 3; ++dx) n[dy][dx] = sg[(r + dy) * 18 + (cc + dx)];
  float c = n[1][1];

  constexpr double Ad = 0.70711;
  constexpr double Bd = 1.0 - Ad;

  const float s0 = n[1][2];
  const float s2 = n[0][1];
  const float s4 = n[1][0];
  const float s6 = n[2][1];
  const float s1 = (float)(Ad * Bd) * n[0][1] + (float)(Ad * Ad) * n[0][2]
                 + (float)(Bd * Bd) * n[1][1] + (float)(Bd * Ad) * n[1][2];
  const float s3 = (float)(Ad * Ad) * n[0][0] + (float)(Ad * Bd) * n[0][1]
                 + (float)(Bd * Ad) * n[1][0] + (float)(Bd * Bd) * n[1][1];
  const float s5 = (float)(Bd * Ad) * n[1][0] + (float)(Bd * Bd) * n[1][1]
                 + (float)(Ad * Ad) * n[2][0] + (float)(Ad * Bd) * n[2][1];
  const float s7 = (float)(Bd * Bd) * n[1][1] + (float)(Bd * Ad) * n[1][2]
                 + (float)(Ad * Bd) * n[2][1] + (float)(Ad * Ad) * n[2][2];

  bool bb[8] = { s0 >= c, s1 >= c, s2 >= c, s3 >= c,
                 s4 >= c, s5 >= c, s6 >= c, s7 >= c };
  int ones = 0, changes = 0;
#pragma unroll
  for (int p = 0; p < 8; ++p) {
    ones += bb[p] ? 1 : 0;
    changes += (bb[p] != bb[(p + 1) & 7]) ? 1 : 0;
  }
  int code = (changes <= 2) ? ones : 9;
  lbpc[(size_t)frame * HWPIX + (ty * 16 + r) * NW + tx * 16 + cc] = (unsigned char)code;

  int m = code;
#pragma unroll
  for (int off = 32; off >= 1; off >>= 1) m = max(m, __shfl_down(m, off, 64));
  __shared__ int wm[4];
  if ((threadIdx.x & 63) == 0) wm[threadIdx.x >> 6] = m;
  __syncthreads();
  if (threadIdx.x == 0)
    blockmax[frame * 196 + tile] = max(max(wm[0], wm[1]), max(wm[2], wm[3]));
}

// ---------------- per-frame max + normalization LUT (bf16) ----------------
__global__ void framemax_tab_kernel(const int* __restrict__ blockmax,
                                    __hip_bfloat16* __restrict__ normtab) {
  int t = threadIdx.x;                                   // 256
  int f = t >> 2, part = t & 3;
  int m = 0;
  for (int j = part; j < 196; j += 4) m = max(m, blockmax[f * 196 + j]);
  m = max(m, __shfl_xor(m, 1, 64));
  m = max(m, __shfl_xor(m, 2, 64));
  if (part == 0) {
    for (int cde = 0; cde < 16; ++cde) {
      float v = (m > 0) ? ((float)cde / (float)m) : (float)cde;  // exact f32 div like ref
      normtab[f * 16 + cde] = __float2bfloat16(v);
    }
  }
}

// ---------------- lbpn: pre-normalized bf16 image -----------------------------
__global__ __launch_bounds__(256) void normlbp_kernel(const unsigned char* __restrict__ lbpc,
                                                      const __hip_bfloat16* __restrict__ normtab,
                                                      __hip_bfloat16* __restrict__ lbpn) {
  int i = blockIdx.x * 256 + threadIdx.x;                // group of 8 pixels
  int frame = (i * 8) / HWPIX;                           // no straddle (50176 % 8 == 0)
  const ushort* tab = (const ushort*)normtab + frame * 16;
  uint2 cds = *(const uint2*)(lbpc + (size_t)i * 8);
  uint o0 = (uint)tab[cds.x & 0xFF] | ((uint)tab[(cds.x >> 8) & 0xFF] << 16);
  uint o1 = (uint)tab[(cds.x >> 16) & 0xFF] | ((uint)tab[cds.x >> 24] << 16);
  uint o2 = (uint)tab[cds.y & 0xFF] | ((uint)tab[(cds.y >> 8) & 0xFF] << 16);
  uint o3 = (uint)tab[(cds.y >> 16) & 0xFF] | ((uint)tab[cds.y >> 24] << 16);
  uint4 ov; ov.x = o0; ov.y = o1; ov.z = o2; ov.w = o3;
  *(uint4*)((ushort*)lbpn + (size_t)i * 8) = ov;
}

// -------- w1m1/w1m2[oc][32] bf16: conv1 K-maps (8 rows x 4 els, el0 = pad) ----
// k = r*4+el. w1m1: r0..2 = kfc0 ky=r (el>=1 -> tap), r3: k=12 = bias, r4..6 =
// kfc1 ky=r-4, r7 = 0. w1m2: r0..2 = kfc2 ky=r, rest 0.
__global__ void w1m_kernel(const float* __restrict__ w1, const float* __restrict__ b1,
                           __hip_bfloat16* __restrict__ w1m1,
                           __hip_bfloat16* __restrict__ w1m2) {
  int o = threadIdx.x;
  if (o >= 64) return;
  float wsum[27];
  for (int t = 0; t < 27; ++t)
    wsum[t] = w1[o * 81 + t] + w1[o * 81 + 27 + t] + w1[o * 81 + 54 + t];
  for (int k = 0; k < 32; ++k) {
    int r = k >> 2, el = k & 3;
    float v1 = 0.0f, v2 = 0.0f;
    if (r < 3 && el >= 1) v1 = wsum[r * 3 + el - 1];
    if (r == 3 && el == 0) v1 = b1[o];
    if (r >= 4 && r < 7 && el >= 1) v1 = wsum[9 + (r - 4) * 3 + el - 1];
    if (r < 3 && el >= 1) v2 = wsum[18 + r * 3 + el - 1];
    w1m1[o * 32 + k] = __float2bfloat16(v1);
    w1m2[o * 32 + k] = __float2bfloat16(v2);
  }
}

// ---------------- w2r[tap][oc][ic] (bf16) from w2[oc][ic][27] ----------------
__global__ __launch_bounds__(256) void w2r_kernel(const float* __restrict__ w2,
                                                  __hip_bfloat16* __restrict__ w2r) {
  int i = blockIdx.x * 256 + threadIdx.x;
  if (i >= 27 * 128 * 64) return;
  int tap = i / (128 * 64);
  int rem = i - tap * (128 * 64);
  int oc = rem >> 6, ic = rem & 63;
  w2r[i] = __float2bfloat16(w2[((size_t)oc * 64 + ic) * 27 + tap]);
}

// ---------------- fused conv1+conv2 MFMA + bias/relu/pool ---------------------
// block = (gg y2-pair, f2, b) via swizzled 1D grid. Per kf phase: conv1 (2 MFMA
// K=32, B-octets loaded DIRECTLY from bf16 lbpn rows) builds h1 slab in LDS;
// conv2 (MFMA) consumes it. Slab layout identical to r7 (conflict-free).
constexpr int ROWB2 = 57 * 256;            // 14,592 B per y1-row

__global__ __launch_bounds__(256, 2) void fused_conv(
    const __hip_bfloat16* __restrict__ lbpn,
    const __hip_bfloat16* __restrict__ w1m1,
    const __hip_bfloat16* __restrict__ w1m2,
    const __hip_bfloat16* __restrict__ w2r,
    const float* __restrict__ b2,
    float* __restrict__ partial) {
  __shared__ __align__(16) char slab[5 * ROWB2];        // 72,960 B

  const int wg = blockIdx.x;                             // 0..895, XCD swizzle
  const int swz = (wg & 7) * 112 + (wg >> 3);
  const int gg = swz % 28;
  const int rem = swz / 28;
  const int f2 = rem & 7;
  const int b = rem >> 3;

  const int tid = threadIdx.x;
  const int lane = tid & 63, w = tid >> 6;
  const int c = lane & 15, q = lane >> 4;
  const int oc0 = w * 32;
  const f32x4 zero4 = {0.f, 0.f, 0.f, 0.f};

  // conv2 per-j decode
  int x2v[7], rb2[7];
#pragma unroll
  for (int j = 0; j < 7; ++j) {
    int pos = j * 16 + c;
    int yo = pos >= 56 ? 1 : 0;
    x2v[j] = pos - 56 * yo;
    rb2[j] = yo * 2 * ROWB2 + x2v[j] * 256;
  }

  // conv1 A fragments (two K=32 maps)
  bf16x8 am1[4], am2[4];
  const __bf16* w1m1b = (const __bf16*)w1m1;
  const __bf16* w1m2b = (const __bf16*)w1m2;
#pragma unroll
  for (int ocg = 0; ocg < 4; ++ocg) {
    am1[ocg] = *(const bf16x8*)(w1m1b + ((ocg * 16 + c) << 5) + q * 8);
    am2[ocg] = *(const bf16x8*)(w1m2b + ((ocg * 16 + c) << 5) + q * 8);
  }

  // per-lane row-slot tables: rid = kfc*3+ky
  const int rid0 = 2 * q - (q >> 1);                     // q:0,1,2,3 -> 0,2,3,5
  const int rid1 = rid0 + 1;
  const bool use1 = (q == 0) || (q == 2);
  const int rid2 = (q == 0) ? 6 : 8;
  const bool use2 = (q <= 1);
  const bool use3 = (q == 0);                            // rid3 = 7
  const bool biasl = (q == 1);                           // slot1 = bias row {1,0,0,0}

  float bias[2][4];
#pragma unroll
  for (int i = 0; i < 2; ++i)
#pragma unroll
    for (int r = 0; r < 4; ++r) bias[i][r] = b2[oc0 + i * 16 + q * 4 + r];

  f32x4 acc[2][7];
#pragma unroll
  for (int i = 0; i < 2; ++i)
#pragma unroll
    for (int j = 0; j < 7; ++j) acc[i][j] = zero4;

  const __bf16* w2rb = (const __bf16*)w2r;
  const char* lbpnb = (const char*)lbpn;

  // zero the static xs=0 pad cells
  if (tid < 40) {
    int r = tid >> 3, u = tid & 7;
    *(int4*)(slab + r * ROWB2 + (u >> 2) * 128 + (u & 3) * 16) = make_int4(0, 0, 0, 0);
  }

  auto rowld = [&](int f1, int rid, bool use, int y1, long xb, uint& lo, uint& hi) {
    int kfc = (rid >= 6) ? 2 : (rid >= 3 ? 1 : 0);
    int ky = rid - kfc * 3;
    int fin = f1 - 1 + kfc;
    int yin = 2 * y1 - 1 + ky;
    bool ok = use && ((unsigned)fin < (unsigned)NF) && ((unsigned)yin < (unsigned)NH);
    long off = ok ? (((long)(b * NF + fin) * HWPIX + (long)yin * NW) * 2 + xb) : 0;
    uint l = *(const uint*)(lbpnb + off);
    uint h = *(const uint*)(lbpnb + off + 4);
    lo = ok ? l : 0u;
    hi = ok ? h : 0u;
  };

  // ---- conv1 phase: build slab from lbpn (direct bf16 row loads) ----
  auto CONV1 = [&](int kf) {
    const int f1 = 2 * f2 - 1 + kf;
    if ((unsigned)f1 >= (unsigned)NF) return;            // slab unread this phase
    for (int fi = w; fi < 35; fi += 4) {
      int rr = fi / 7, fx = fi - 7 * rr;                 // y1 = 4gg-1+rr, x1 = fx*16+c
      int y1 = 4 * gg - 1 + rr;
      int xs = fx * 16 + c + 1;
      int t = xs >> 1, k7 = t & 7, sub = xs & 1;
      char* wbase = slab + rr * ROWB2 + t * 256 + (q & 1) * 8;
      if ((unsigned)y1 < 112u) {
        const int x1 = fx * 16 + c;
        const long xb = (long)(4 * x1 - 4);              // bf16 els: x = 2x1-2..2x1+1
        uint r0l, r0h, r1l, r1h, r2l, r2h, r3l, r3h;
        rowld(f1, rid0, true, y1, xb, r0l, r0h);
        rowld(f1, rid1, use1, y1, xb, r1l, r1h);
        rowld(f1, rid2, use2, y1, xb, r2l, r2h);
        rowld(f1, 7,    use3, y1, xb, r3l, r3h);
        if (x1 == 0) {                                   // zero el1 (x = -1 pad)
          r0l &= 0xFFFFu; r1l &= 0xFFFFu; r2l &= 0xFFFFu; r3l &= 0xFFFFu;
        }
        if (biasl) { r1l = 0x3F80u; r1h = 0u; }          // bias row: input 1.0
        union U8 { bf16x8 v; uint u[4]; } b1u, b2u;
        b1u.u[0] = r0l; b1u.u[1] = r0h; b1u.u[2] = r1l; b1u.u[3] = r1h;
        b2u.u[0] = r2l; b2u.u[1] = r2h; b2u.u[2] = r3l; b2u.u[3] = r3h;
#pragma unroll
        for (int ocg = 0; ocg < 4; ++ocg) {
          f32x4 a = MFMA16(am1[ocg], b1u.v, zero4);
          a = MFMA16(am2[ocg], b2u.v, a);
          ushort4 o;
          o.x = bf16u(fmaxf(a[0], 0.0f));
          o.y = bf16u(fmaxf(a[1], 0.0f));
          o.z = bf16u(fmaxf(a[2], 0.0f));
          o.w = bf16u(fmaxf(a[3], 0.0f));
          int ich = ocg >> 1;
          int g8 = sub * 4 + (ocg & 1) * 2 + (q >> 1);
          *(ushort4*)(wbase + ich * 128 + ((g8 ^ k7) << 4)) = o;
        }
      } else {
        ushort4 z; z.x = z.y = z.z = z.w = 0;
#pragma unroll
        for (int ocg = 0; ocg < 4; ++ocg) {
          int ich = ocg >> 1;
          int g8 = sub * 4 + (ocg & 1) * 2 + (q >> 1);
          *(ushort4*)(wbase + ich * 128 + ((g8 ^ k7) << 4)) = z;
        }
      }
    }
  };

  CONV1(0);

  for (int kf = 0; kf < 3; ++kf) {
    __syncthreads();                                     // slab(kf) ready
    const int f1 = 2 * f2 - 1 + kf;
    const bool fok = (unsigned)f1 < (unsigned)NF;

    // ---- conv2 phase: consume slab ----
    if (fok) {
#pragma unroll
      for (int ky = 0; ky < 3; ++ky) {
#pragma unroll
        for (int kx = 0; kx < 3; ++kx) {
          const int tap = kf * 9 + ky * 3 + kx;
          const int sx = kx >> 1;
          const int sb4 = (kx & 1) * 4 + q;
          const int immr = ky * ROWB2 + sx * 256;
#pragma unroll
          for (int ich = 0; ich < 2; ++ich) {
            const __bf16* wtap = w2rb + (((size_t)tap * 128 + oc0 + c) << 6)
                               + ich * 32 + q * 8;
            bf16x8 a0 = *(const bf16x8*)(wtap);
            bf16x8 a1 = *(const bf16x8*)(wtap + (16 << 6));
#pragma unroll
            for (int j = 0; j < 7; ++j) {
              int slot = sb4 ^ ((x2v[j] + sx) & 7);
              bf16x8 bv = *(const bf16x8*)(slab + rb2[j] + immr + ich * 128 + (slot << 4));
              acc[0][j] = MFMA16(a0, bv, acc[0][j]);
              acc[1][j] = MFMA16(a1, bv, acc[1][j]);
            }
          }
        }
      }
    }

    __syncthreads();                                     // slab reads done
    if (kf < 2) CONV1(kf + 1);
  }

  // ---- epilogue: bias + relu + pool over 112 positions, reduce 16 lanes ----
#pragma unroll
  for (int i = 0; i < 2; ++i) {
#pragma unroll
    for (int r = 0; r < 4; ++r) {
      float s = 0.0f;
#pragma unroll
      for (int j = 0; j < 7; ++j) s += fmaxf(acc[i][j][r] + bias[i][r], 0.0f);
      s += __shfl_xor(s, 1);
      s += __shfl_xor(s, 2);
      s += __shfl_xor(s, 4);
      s += __shfl_xor(s, 8);
      if (c == 0) {
        int oc = oc0 + i * 16 + q * 4 + r;
        partial[((size_t)b * OC2 + oc) * 224 + f2 * 28 + gg] = s;
      }
    }
  }
}

__global__ void final_kernel(const float* __restrict__ partial, float* __restrict__ out) {
  int i = blockIdx.x * 256 + threadIdx.x;                // < 512
  float s = 0.0f;
  for (int j = 0; j < 224; ++j) s += partial[(size_t)i * 224 + j];
  out[i] = s / 25088.0f;
}

extern "C" void kernel_launch(void* const* d_in, const int* in_sizes, int n_in,
                              void* d_out, int out_size, void* d_ws, size_t ws_size,
                              hipStream_t stream) {
  const float* x  = (const float*)d_in[0];
  const float* w1 = (const float*)d_in[1];
  const float* b1 = (const float*)d_in[2];
  const float* w2 = (const float*)d_in[3];
  const float* b2 = (const float*)d_in[4];
  float* out = (float*)d_out;

  char* ws = (char*)d_ws;
  unsigned char* lbpc = (unsigned char*)ws;                    // 3,211,264 B
  int* blockmax = (int*)(ws + 3211264);                        // 50,176 B
  __hip_bfloat16* normtab = (__hip_bfloat16*)(ws + 3261440);   // 2,048 B
  float* partial = (float*)(ws + 3263488);                     // 458,752 B
  __hip_bfloat16* w2r = (__hip_bfloat16*)(ws + 3722240);       // 442,368 B
  __hip_bfloat16* w1m1 = (__hip_bfloat16*)(ws + 4164608);      // 4,096 B
  __hip_bfloat16* w1m2 = (__hip_bfloat16*)(ws + 4168704);      // 4,096 B
  __hip_bfloat16* lbpn = (__hip_bfloat16*)(ws + 4172800);      // 6,422,528 B -> 10,595,328

  w1m_kernel<<<1, 64, 0, stream>>>(w1, b1, w1m1, w1m2);
  w2r_kernel<<<(27 * 128 * 64 + 255) / 256, 256, 0, stream>>>(w2, w2r);
  graylbp_kernel<<<dim3(196, NB * NF), 256, 0, stream>>>(x, lbpc, blockmax);
  framemax_tab_kernel<<<1, 256, 0, stream>>>(blockmax, normtab);
  normlbp_kernel<<<NPIX / 8 / 256, 256, 0, stream>>>(lbpc, normtab, lbpn);
  fused_conv<<<896, 256, 0, stream>>>(lbpn, w1m1, w1m2, w2r, b2, partial);
  final_kernel<<<2, 256, 0, stream>>>(partial, out);
}